// Round 4
// baseline (204.449 us; speedup 1.0000x reference)
//
#include <hip/hip_runtime.h>

// LocalMean: 5x5 box filter, reflect padding, (32,3,512,512) fp32.
// R3: copy-like structure. R2 (LDS phases + barriers) stuck at 2.7 TB/s while
// the harness memset hit 6.8 TB/s -> phase/barrier stalls were the limit.
// Now: one output float4-quad per thread, straight-line code, 15 independent
// loads -> ~70 VALU -> 1 store. No LDS, no barriers, no loops. L1/L2/L3
// absorb the horizontal/vertical read overlap (input is L3-resident).

constexpr int H  = 512;
constexpr int W  = 512;
constexpr int QX = W / 4;   // 128 quads per row

__global__ __launch_bounds__(256) void localmean_kernel(const float* __restrict__ in,
                                                        float* __restrict__ out) {
    const int t     = threadIdx.x;
    const int q     = t & (QX - 1);            // x-quad 0..127
    const int rp    = blockIdx.x & (H / 2 - 1);// row-pair 0..255
    const int plane = blockIdx.x >> 8;         // 0..95
    const int y     = rp * 2 + (t >> 7);       // output row

    const float* pin = in + (size_t)plane * H * W;

    // ---- load phase: 15 independent loads, all issued before any use.
    float4 cu[5];
    float2 lf[5], rt[5];
    const int xl = (q > 0)      ? 4 * q - 2 : 0;        // clamped addr; fixed below
    const int xr = (q < QX - 1) ? 4 * q + 4 : 4 * q - 4;
    #pragma unroll
    for (int k = 0; k < 5; ++k) {
        int gy = y - 2 + k;                    // reflect in y
        gy = (gy < 0) ? -gy : gy;
        gy = (gy >= H) ? (2 * H - 2 - gy) : gy;
        const float* row = pin + (size_t)gy * W;
        cu[k] = *(const float4*)(row + 4 * q);
        lf[k] = *(const float2*)(row + xl);
        rt[k] = *(const float2*)(row + xr);
    }

    // ---- compute: per-row 5-tap horizontal sums, accumulate vertically.
    float4 acc = make_float4(0.f, 0.f, 0.f, 0.f);
    #pragma unroll
    for (int k = 0; k < 5; ++k) {
        float2 l = lf[k], r = rt[k];
        if (q == 0)      { l.x = cu[k].z; l.y = cu[k].y; }  // reflect e[-2],e[-1]
        if (q == QX - 1) { r.x = cu[k].z; r.y = cu[k].y; }  // reflect e[512],e[513]
        float s = cu[k].x + cu[k].y + cu[k].z + cu[k].w;
        acc.x += (s - cu[k].w) + l.x + l.y;   // x-2..x+2
        acc.y += s + l.y;                     // x-1..x+3
        acc.z += s + r.x;                     // x  ..x+4
        acc.w += (s - cu[k].x) + r.x + r.y;   // x+1..x+5
    }
    const float inv = 1.0f / 25.0f;
    acc.x *= inv; acc.y *= inv; acc.z *= inv; acc.w *= inv;

    ((float4*)(out + (size_t)plane * H * W + (size_t)y * W))[q] = acc;
}

extern "C" void kernel_launch(void* const* d_in, const int* in_sizes, int n_in,
                              void* d_out, int out_size, void* d_ws, size_t ws_size,
                              hipStream_t stream) {
    const float* in = (const float*)d_in[0];
    float* out = (float*)d_out;
    const int planes = in_sizes[0] / (H * W);   // 96
    dim3 grid(planes * (H / 2));                // 24576 blocks
    dim3 block(256);
    localmean_kernel<<<grid, block, 0, stream>>>(in, out);
}